// Round 6
// baseline (45.795 us; speedup 1.0000x reference)
//
#include <hip/hip_runtime.h>

typedef float v2f __attribute__((ext_vector_type(2)));
typedef float v4f __attribute__((ext_vector_type(4)));

#define BLK 256
#define IPT 4                 // i-particles per thread
#define TI (BLK * IPT)        // 1024 i's per block
#define TJ 32                 // j's per block
#define RTI (TI / TJ)         // 32 j-tiles per i-tile
#define G_CONST 0.001f
#define EPS_CONST 1e-6f

// Triangular tiling over unordered pairs (1.6x less work than full N^2):
//  - full blocks: j-tile strictly below i-tile -> every unordered cross pair
//    computed exactly once, weight 1.
//  - diag blocks: j-tile inside i-tile -> full rectangle computed (both orders
//    + selfs), selfs subtracted bit-exactly, weight 0.5.
// Block decode: for i-tile a there are RTI*a full + RTI diag = RTI*(a+1) blocks.
__global__ __launch_bounds__(BLK, 4)
void grav_kernel(const float* __restrict__ q, const float* __restrict__ m,
                 float* __restrict__ out, int N) {
  const int b   = blockIdx.z;
  const int tid = threadIdx.x;

  // Decode blockIdx.x -> (i-tile a, j-tile jt). Max 4 iterations, all scalar.
  int rel = blockIdx.x;
  int a = 0;
  while (rel >= RTI * (a + 1)) { rel -= RTI * (a + 1); ++a; }
  const int jt   = rel;                  // j-tile in [0, RTI*(a+1))
  const bool diag = (jt >= RTI * a);     // j-range inside i-range?
  const int i0 = a * TI;
  const int j0 = jt * TJ;

  __shared__ float xs[TJ], ys[TJ], zs[TJ], ms[TJ];
  __shared__ float wsum[4];

  const float* qb = q + (size_t)b * N * 3;

  if (tid < TJ) {
    const int j = j0 + tid;
    xs[tid] = qb[3 * j + 0];
    ys[tid] = qb[3 * j + 1];
    zs[tid] = qb[3 * j + 2];
    ms[tid] = m[j];
  }

  v2f xi2[IPT], yi2[IPT], zi2[IPT];
  float mi[IPT];
#pragma unroll
  for (int s = 0; s < IPT; ++s) {
    const int i = i0 + s * BLK + tid;
    const float x = qb[3 * i + 0];
    const float y = qb[3 * i + 1];
    const float z = qb[3 * i + 2];
    xi2[s] = (v2f){x, x};
    yi2[s] = (v2f){y, y};
    zi2[s] = (v2f){z, z};
    mi[s]  = m[i];
  }

  __syncthreads();

  const v2f eps2 = {EPS_CONST, EPS_CONST};
  v2f acc[IPT] = {};

  for (int k = 0; k < TJ; k += 4) {
    const v4f jx = *(const v4f*)&xs[k];   // uniform addr -> broadcast read
    const v4f jy = *(const v4f*)&ys[k];
    const v4f jz = *(const v4f*)&zs[k];
    const v4f jm = *(const v4f*)&ms[k];
    const v2f jx0 = {jx.x, jx.y}, jx1 = {jx.z, jx.w};
    const v2f jy0 = {jy.x, jy.y}, jy1 = {jy.z, jy.w};
    const v2f jz0 = {jz.x, jz.y}, jz1 = {jz.z, jz.w};
    const v2f jm0 = {jm.x, jm.y}, jm1 = {jm.z, jm.w};

#pragma unroll
    for (int s = 0; s < IPT; ++s) {
      const v2f dx0 = jx0 - xi2[s], dy0 = jy0 - yi2[s], dz0 = jz0 - zi2[s];
      const v2f dx1 = jx1 - xi2[s], dy1 = jy1 - yi2[s], dz1 = jz1 - zi2[s];

      v2f r0 = __builtin_elementwise_fma(dz0, dz0, eps2);
      v2f r1 = __builtin_elementwise_fma(dz1, dz1, eps2);
      r0 = __builtin_elementwise_fma(dy0, dy0, r0);
      r1 = __builtin_elementwise_fma(dy1, dy1, r1);
      r0 = __builtin_elementwise_fma(dx0, dx0, r0);
      r1 = __builtin_elementwise_fma(dx1, dx1, r1);

      const v2f ri0 = {__builtin_amdgcn_rsqf(r0.x), __builtin_amdgcn_rsqf(r0.y)};
      const v2f ri1 = {__builtin_amdgcn_rsqf(r1.x), __builtin_amdgcn_rsqf(r1.y)};

      acc[s] = __builtin_elementwise_fma(jm0, ri0, acc[s]);
      acc[s] = __builtin_elementwise_fma(jm1, ri1, acc[s]);
    }
  }

  // Self-terms (only possible in diag blocks): at i==j the fma chain yields
  // r2 == EPS exactly, contributing mi*rsq(EPS); subtract the identical value.
  float tsum = 0.f;
#pragma unroll
  for (int s = 0; s < IPT; ++s) {
    const int i = i0 + s * BLK + tid;
    float h = acc[s].x + acc[s].y;
    if (i >= j0 && i < j0 + TJ) h -= mi[s] * __builtin_amdgcn_rsqf(EPS_CONST);
    tsum += mi[s] * h;
  }

#pragma unroll
  for (int off = 32; off > 0; off >>= 1) tsum += __shfl_down(tsum, off);
  const int wid  = tid >> 6;
  const int lane = tid & 63;
  if (lane == 0) wsum[wid] = tsum;
  __syncthreads();
  if (tid == 0) {
    const float s = (wsum[0] + wsum[1]) + (wsum[2] + wsum[3]);
    const float scale = diag ? (-0.5f * G_CONST) : (-G_CONST);
    atomicAdd(out + b, s * scale);
  }
}

extern "C" void kernel_launch(void* const* d_in, const int* in_sizes, int n_in,
                              void* d_out, int out_size, void* d_ws, size_t ws_size,
                              hipStream_t stream) {
  const float* q = (const float*)d_in[0];
  const float* m = (const float*)d_in[1];
  float* out = (float*)d_out;

  const int N = in_sizes[1];
  const int B = in_sizes[0] / (N * 3);

  hipMemsetAsync(out, 0, (size_t)out_size * sizeof(float), stream);

  const int nti = N / TI;                         // 4 i-tiles
  const int bpb = RTI * nti * (nti + 1) / 2;      // 320 blocks per batch
  dim3 grid(bpb, 1, B);                           // 2560 blocks
  grav_kernel<<<grid, BLK, 0, stream>>>(q, m, out, N);
}

// Round 7
// 41.415 us; speedup vs baseline: 1.1058x; 1.1058x over previous
//
#include <hip/hip_runtime.h>

typedef float v2f __attribute__((ext_vector_type(2)));
typedef float v4f __attribute__((ext_vector_type(4)));

#define BLK 256
#define IPT 4                 // i-particles per thread
#define TI (BLK * IPT)        // 1024 i's per block
#define TJ 64                 // j's staged per block
#define G_CONST 0.001f
#define EPS_CONST 1e-6f

// Full N^2, fat blocks (65K pairs/block). 6 waves/SIMD for stall hiding;
// register-prefetch of the next j-group keeps lgkm waits off the critical path.
__global__ __launch_bounds__(BLK, 6)
void grav_kernel(const float* __restrict__ q, const float* __restrict__ m,
                 float* __restrict__ out, int N) {
  const int b   = blockIdx.z;
  const int tid = threadIdx.x;
  const int j0  = blockIdx.y * TJ;
  const int i0  = blockIdx.x * TI;

  __shared__ float xs[TJ], ys[TJ], zs[TJ], ms[TJ];
  __shared__ float wsum[4];

  const float* qb = q + (size_t)b * N * 3;

  if (tid < TJ) {
    const int j = j0 + tid;
    xs[tid] = qb[3 * j + 0];
    ys[tid] = qb[3 * j + 1];
    zs[tid] = qb[3 * j + 2];
    ms[tid] = m[j];
  }

  // Per-thread i-slots (scalar regs; compiler splats via op_sel/pk as needed).
  float xi[IPT], yi[IPT], zi[IPT], mi[IPT];
#pragma unroll
  for (int s = 0; s < IPT; ++s) {
    const int i = i0 + s * BLK + tid;
    xi[s] = qb[3 * i + 0];
    yi[s] = qb[3 * i + 1];
    zi[s] = qb[3 * i + 2];
    mi[s] = m[i];
  }

  __syncthreads();

  const v2f eps2 = {EPS_CONST, EPS_CONST};
  v2f acc[IPT] = {};

  // Prefetched j-group loop: group k+4 is loaded while group k computes.
  v4f jx = *(const v4f*)&xs[0];
  v4f jy = *(const v4f*)&ys[0];
  v4f jz = *(const v4f*)&zs[0];
  v4f jm = *(const v4f*)&ms[0];

  for (int k = 0; k < TJ; k += 4) {
    const int kn = (k + 4) & (TJ - 1);      // wrap: last prefetch is harmless
    const v4f nx = *(const v4f*)&xs[kn];
    const v4f ny = *(const v4f*)&ys[kn];
    const v4f nz = *(const v4f*)&zs[kn];
    const v4f nm = *(const v4f*)&ms[kn];

    const v2f jx0 = {jx.x, jx.y}, jx1 = {jx.z, jx.w};
    const v2f jy0 = {jy.x, jy.y}, jy1 = {jy.z, jy.w};
    const v2f jz0 = {jz.x, jz.y}, jz1 = {jz.z, jz.w};
    const v2f jm0 = {jm.x, jm.y}, jm1 = {jm.z, jm.w};

#pragma unroll
    for (int s = 0; s < IPT; ++s) {
      const v2f xi2 = {xi[s], xi[s]}, yi2 = {yi[s], yi[s]}, zi2 = {zi[s], zi[s]};
      const v2f dx0 = jx0 - xi2, dy0 = jy0 - yi2, dz0 = jz0 - zi2;
      const v2f dx1 = jx1 - xi2, dy1 = jy1 - yi2, dz1 = jz1 - zi2;

      v2f r0 = __builtin_elementwise_fma(dz0, dz0, eps2);
      v2f r1 = __builtin_elementwise_fma(dz1, dz1, eps2);
      r0 = __builtin_elementwise_fma(dy0, dy0, r0);
      r1 = __builtin_elementwise_fma(dy1, dy1, r1);
      r0 = __builtin_elementwise_fma(dx0, dx0, r0);
      r1 = __builtin_elementwise_fma(dx1, dx1, r1);

      const v2f ri0 = {__builtin_amdgcn_rsqf(r0.x), __builtin_amdgcn_rsqf(r0.y)};
      const v2f ri1 = {__builtin_amdgcn_rsqf(r1.x), __builtin_amdgcn_rsqf(r1.y)};

      acc[s] = __builtin_elementwise_fma(jm0, ri0, acc[s]);
      acc[s] = __builtin_elementwise_fma(jm1, ri1, acc[s]);
    }

    jx = nx; jy = ny; jz = nz; jm = nm;
  }

  // Self-term: at i==j the fma chain yields r2 == EPS exactly, contributing
  // mi*rsq(EPS); subtract the identical value.
  float tsum = 0.f;
#pragma unroll
  for (int s = 0; s < IPT; ++s) {
    const int i = i0 + s * BLK + tid;
    float h = acc[s].x + acc[s].y;
    if (i >= j0 && i < j0 + TJ) h -= mi[s] * __builtin_amdgcn_rsqf(EPS_CONST);
    tsum += mi[s] * h;
  }

  // Block reduction: 64-lane shuffle, then across 4 waves via LDS.
#pragma unroll
  for (int off = 32; off > 0; off >>= 1) tsum += __shfl_down(tsum, off);
  const int wid  = tid >> 6;
  const int lane = tid & 63;
  if (lane == 0) wsum[wid] = tsum;
  __syncthreads();
  if (tid == 0) {
    const float s = (wsum[0] + wsum[1]) + (wsum[2] + wsum[3]);
    atomicAdd(out + b, s * (-0.5f * G_CONST));
  }
}

extern "C" void kernel_launch(void* const* d_in, const int* in_sizes, int n_in,
                              void* d_out, int out_size, void* d_ws, size_t ws_size,
                              hipStream_t stream) {
  const float* q = (const float*)d_in[0];
  const float* m = (const float*)d_in[1];
  float* out = (float*)d_out;

  const int N = in_sizes[1];
  const int B = in_sizes[0] / (N * 3);

  hipMemsetAsync(out, 0, (size_t)out_size * sizeof(float), stream);

  dim3 grid(N / TI, N / TJ, B);   // 4 x 64 x 8 = 2048 blocks
  grav_kernel<<<grid, BLK, 0, stream>>>(q, m, out, N);
}